// Round 8
// baseline (359.598 us; speedup 1.0000x reference)
//
#include <hip/hip_runtime.h>
#include <hip/hip_bf16.h>

// ---------------------------------------------------------------------------
// SelfAttention: y = proj(attn(qkv(x)))   B=4 T=2048 C=1024 H=16 HD=64
// Inputs/outputs are FLOAT32 (per reference); pad_mask is int32.
// Internally: convert to bf16, MFMA 16x16x32 bf16, accumulate f32.
// GEMMs use the m97 structure: 128x128 tile, BK=64, global_load_lds(16B).
// ---------------------------------------------------------------------------

using short8  = __attribute__((ext_vector_type(8))) short;
using float4_ = __attribute__((ext_vector_type(4))) float;

#define Bb   4
#define Tt   2048
#define Cc   1024
#define Hh   16
#define HDd  64

// base-2 exp via the direct gfx950 intrinsic (one v_exp_f32).
// (__exp2f collides with a glibc math.h macro -> host-fn compile error.)
#define EXP2F(x) __builtin_amdgcn_exp2f(x)

__device__ __forceinline__ float bf2f(unsigned short u) {
    union { float f; unsigned int i; } x; x.i = ((unsigned int)u) << 16; return x.f;
}
__device__ __forceinline__ unsigned short f2bf(float f) {
    union { float f; unsigned int i; } x; x.f = f;
    unsigned int r = x.i + 0x7fff + ((x.i >> 16) & 1);
    return (unsigned short)(r >> 16);
}
__device__ __forceinline__ float4_ bmfma(short8 a, short8 b, float4_ c) {
    return __builtin_amdgcn_mfma_f32_16x16x32_bf16(a, b, c, 0, 0, 0);
}
// async 16B global -> LDS (dest must be wave-uniform base + lane*16)
__device__ __forceinline__ void gl2lds16(const unsigned short* g, unsigned short* l) {
    __builtin_amdgcn_global_load_lds(
        (const __attribute__((address_space(1))) void*)g,
        (__attribute__((address_space(3))) void*)l, 16, 0, 0);
}

// ---------------------------------------------------------------------------
// x f32 -> bf16 (flat)
// ---------------------------------------------------------------------------
__global__ __launch_bounds__(256) void convert_f32_bf16(
    const float* __restrict__ in, unsigned short* __restrict__ out)
{
    size_t idx = ((size_t)blockIdx.x * 256 + threadIdx.x) * 8;
    float4_ f0 = *(const float4_*)&in[idx];
    float4_ f1 = *(const float4_*)&in[idx + 4];
    short8 h;
    h[0] = (short)f2bf(f0[0]); h[1] = (short)f2bf(f0[1]);
    h[2] = (short)f2bf(f0[2]); h[3] = (short)f2bf(f0[3]);
    h[4] = (short)f2bf(f1[0]); h[5] = (short)f2bf(f1[1]);
    h[6] = (short)f2bf(f1[2]); h[7] = (short)f2bf(f1[3]);
    *(short8*)&out[idx] = h;
}

// ---------------------------------------------------------------------------
// Transpose + convert: in f32 [R][Ccols] -> out bf16 [Ccols][R]
// ---------------------------------------------------------------------------
__global__ __launch_bounds__(256) void transpose_f32_bf16(
    const float* __restrict__ in, unsigned short* __restrict__ out,
    int R, int Ccols)
{
    __shared__ unsigned short tile[32][33];
    int c0 = blockIdx.x * 32, r0 = blockIdx.y * 32;
    int tx = threadIdx.x & 31, ty = threadIdx.x >> 5;   // ty 0..7
    for (int o = 0; o < 32; o += 8)
        tile[ty + o][tx] = f2bf(in[(size_t)(r0 + ty + o) * Ccols + c0 + tx]);
    __syncthreads();
    for (int o = 0; o < 32; o += 8)
        out[(size_t)(c0 + ty + o) * R + r0 + tx] = tile[tx][ty + o];
}

// ---------------------------------------------------------------------------
// m97-style GEMM main loop: C = A[M][K](bf16) * Bt[N][K](bf16)^T
// 128x128 block tile, BK=64, 4 waves each computing 64x64 via 4x4 MFMA.
// ---------------------------------------------------------------------------
#define GBK 64

__device__ __forceinline__ void gemm128_main(
    const unsigned short* __restrict__ A, const unsigned short* __restrict__ Bt,
    int K, int m0, int n0,
    unsigned short* As, unsigned short* Bs, float4_ acc[4][4])
{
    int tid  = threadIdx.x;
    int wave = tid >> 6, lane = tid & 63;
    int wm = (wave >> 1) * 64, wn = (wave & 1) * 64;
    int lr = lane & 15, lg = lane >> 4;
    int srow = tid >> 3;            // 0..31
    int scol = (tid & 7) * 8;       // 0..56

    for (int k0 = 0; k0 < K; k0 += GBK) {
        #pragma unroll
        for (int j = 0; j < 4; j++) {
            int row = j * 32 + srow;
            gl2lds16(&A [(size_t)(m0 + row) * K + k0 + scol], &As[row * GBK + scol]);
            gl2lds16(&Bt[(size_t)(n0 + row) * K + k0 + scol], &Bs[row * GBK + scol]);
        }
        __syncthreads();
        #pragma unroll
        for (int ks = 0; ks < GBK; ks += 32) {
            short8 af[4], bf[4];
            #pragma unroll
            for (int i = 0; i < 4; i++) {
                af[i] = *(const short8*)&As[(wm + i * 16 + lr) * GBK + ks + lg * 8];
                bf[i] = *(const short8*)&Bs[(wn + i * 16 + lr) * GBK + ks + lg * 8];
            }
            #pragma unroll
            for (int i = 0; i < 4; i++)
                #pragma unroll
                for (int j = 0; j < 4; j++)
                    acc[i][j] = bmfma(af[i], bf[j], acc[i][j]);
        }
        __syncthreads();
    }
}

// Q pre-scale: 1/sqrt(64) * log2(e) -> attn uses exp2 directly.
#define QSCALE 0.180336879f

__global__ __launch_bounds__(256) void gemm_qkv(
    const unsigned short* __restrict__ A,   // x: [8192][1024] bf16
    const unsigned short* __restrict__ Bt,  // w_attn^T: [3072][1024] bf16
    unsigned short* __restrict__ Q,         // [B][H][T][HD] bf16 (pre-scaled)
    unsigned short* __restrict__ Ko,
    unsigned short* __restrict__ V)
{
    __shared__ unsigned short As[128 * GBK];
    __shared__ unsigned short Bs[128 * GBK];
    int m0 = blockIdx.x * 128, n0 = blockIdx.y * 128;
    float4_ acc[4][4] = {};
    gemm128_main(A, Bt, 1024, m0, n0, As, Bs, acc);

    int lane = threadIdx.x & 63, wave = threadIdx.x >> 6;
    int wm = (wave >> 1) * 64, wn = (wave & 1) * 64;
    int lr = lane & 15, lg = lane >> 4;
    #pragma unroll
    for (int i = 0; i < 4; i++)
        #pragma unroll
        for (int j = 0; j < 4; j++) {
            int n = n0 + wn + 16 * j + lr;
            int which = n >> 10;
            int c = n & 1023;
            int h = c >> 6, d = c & 63;
            unsigned short* dst = (which == 0) ? Q : ((which == 1) ? Ko : V);
            float sc2 = (which == 0) ? QSCALE : 1.0f;
            #pragma unroll
            for (int r = 0; r < 4; r++) {
                int m = m0 + wm + 16 * i + lg * 4 + r;
                int b = m >> 11, t = m & 2047;
                dst[(((size_t)(b * Hh + h) * Tt) + t) * HDd + d] = f2bf(acc[i][j][r] * sc2);
            }
        }
}

__global__ __launch_bounds__(256) void gemm_proj(
    const unsigned short* __restrict__ A,   // y: [8192][1024] bf16
    const unsigned short* __restrict__ Bt,  // w_proj^T: [1024][1024] bf16
    const float* __restrict__ bias,         // [1024] f32
    float* __restrict__ Out)                // [8192][1024] f32
{
    __shared__ unsigned short As[128 * GBK];
    __shared__ unsigned short Bs[128 * GBK];
    int m0 = blockIdx.x * 128, n0 = blockIdx.y * 128;
    float4_ acc[4][4] = {};
    gemm128_main(A, Bt, 1024, m0, n0, As, Bs, acc);

    int lane = threadIdx.x & 63, wave = threadIdx.x >> 6;
    int wm = (wave >> 1) * 64, wn = (wave & 1) * 64;
    int lr = lane & 15, lg = lane >> 4;
    #pragma unroll
    for (int i = 0; i < 4; i++)
        #pragma unroll
        for (int j = 0; j < 4; j++) {
            int n = n0 + wn + 16 * j + lr;
            float bv = bias[n];
            #pragma unroll
            for (int r = 0; r < 4; r++) {
                int m = m0 + wm + 16 * i + lg * 4 + r;
                Out[(size_t)m * 1024 + n] = acc[i][j][r] + bv;
            }
        }
}

// ---------------------------------------------------------------------------
// Flash attention, PAIRED q-tiles (qbA=qpair, qbB=31-qpair): every block does
// exactly 33 tile-computes -> perfect balance; 1024 blocks = 4/CU co-resident.
// Macro-inlined tile body (round-4 regression was scratch spill from helper-fn
// array args). P has its own LDS region (Kt must stay intact for tile A).
// Q pre-scaled by 1/8*log2(e): softmax uses exp2 (no per-element mul).
// ---------------------------------------------------------------------------
#define DPAD 72   // padded row stride (elems) = 144B

// One 64-key tile against one 16-row q-tile (per wave). All names from
// enclosing scope: k0, lr, lg, Kt, Vt, Pw, pmask[4].
#define ATTN_TILE(q0X, qX0, qX1, mX, lX, oX)                                   \
    {                                                                          \
        float4_ s[4];                                                          \
        _Pragma("unroll")                                                      \
        for (int nt = 0; nt < 4; nt++) {                                       \
            short8 kf0 = *(const short8*)&Kt[(nt * 16 + lr) * DPAD + lg * 8];  \
            short8 kf1 = *(const short8*)&Kt[(nt * 16 + lr) * DPAD + 32 + lg * 8]; \
            float4_ a = (float4_){0.f, 0.f, 0.f, 0.f};                         \
            a = bmfma(qX0, kf0, a);                                            \
            a = bmfma(qX1, kf1, a);                                            \
            s[nt] = a;                                                         \
        }                                                                      \
        bool interior = (k0 + 63 <= (q0X));                                    \
        if (interior) {                                                        \
            _Pragma("unroll")                                                  \
            for (int nt = 0; nt < 4; nt++) {                                   \
                _Pragma("unroll")                                              \
                for (int r = 0; r < 4; r++) s[nt][r] += pmask[nt];             \
            }                                                                  \
        } else {                                                               \
            _Pragma("unroll")                                                  \
            for (int nt = 0; nt < 4; nt++) {                                   \
                int key = k0 + nt * 16 + lr;                                   \
                _Pragma("unroll")                                              \
                for (int r = 0; r < 4; r++) {                                  \
                    int qrow = (q0X) + lg * 4 + r;                             \
                    float sv = s[nt][r] + pmask[nt];                           \
                    if (key > qrow) sv = -1e30f;                               \
                    s[nt][r] = sv;                                             \
                }                                                              \
            }                                                                  \
        }                                                                      \
        float mn[4], alpha[4];                                                 \
        _Pragma("unroll")                                                      \
        for (int r = 0; r < 4; r++) {                                          \
            float v = fmaxf(fmaxf(s[0][r], s[1][r]), fmaxf(s[2][r], s[3][r])); \
            _Pragma("unroll")                                                  \
            for (int off = 1; off < 16; off <<= 1)                             \
                v = fmaxf(v, __shfl_xor(v, off, 64));                          \
            float m_new = fmaxf(mX[r], v);                                     \
            alpha[r] = EXP2F(mX[r] - m_new);                                   \
            mn[r] = m_new;                                                     \
        }                                                                      \
        float rsum[4] = {0.f, 0.f, 0.f, 0.f};                                  \
        _Pragma("unroll")                                                      \
        for (int nt = 0; nt < 4; nt++)                                         \
            _Pragma("unroll")                                                  \
            for (int r = 0; r < 4; r++) {                                      \
                float p = EXP2F(s[nt][r] - mn[r]);                             \
                s[nt][r] = p;                                                  \
                rsum[r] += p;                                                  \
            }                                                                  \
        _Pragma("unroll")                                                      \
        for (int r = 0; r < 4; r++) {                                          \
            float v = rsum[r];                                                 \
            _Pragma("unroll")                                                  \
            for (int off = 1; off < 16; off <<= 1)                             \
                v += __shfl_xor(v, off, 64);                                   \
            lX[r] = lX[r] * alpha[r] + v;                                      \
            mX[r] = mn[r];                                                     \
        }                                                                      \
        _Pragma("unroll")                                                      \
        for (int nt = 0; nt < 4; nt++)                                         \
            _Pragma("unroll")                                                  \
            for (int r = 0; r < 4; r++)                                        \
                Pw[(lg * 4 + r) * DPAD + nt * 16 + lr] = f2bf(s[nt][r]);       \
        _Pragma("unroll")                                                      \
        for (int dt = 0; dt < 4; dt++)                                         \
            _Pragma("unroll")                                                  \
            for (int r = 0; r < 4; r++)                                        \
                oX[dt][r] *= alpha[r];                                         \
        short8 pf0 = *(const short8*)&Pw[lr * DPAD + lg * 8];                  \
        short8 pf1 = *(const short8*)&Pw[lr * DPAD + 32 + lg * 8];             \
        _Pragma("unroll")                                                      \
        for (int dt = 0; dt < 4; dt++) {                                       \
            int d = dt * 16 + lr;                                              \
            short8 vf0 = *(const short8*)&Vt[d * DPAD + ((lg ^ (d >> 3)) << 3)];       \
            short8 vf1 = *(const short8*)&Vt[d * DPAD + (((lg + 4) ^ (d >> 3)) << 3)]; \
            oX[dt] = bmfma(pf0, vf0, oX[dt]);                                  \
            oX[dt] = bmfma(pf1, vf1, oX[dt]);                                  \
        }                                                                      \
    }

__global__ __launch_bounds__(256, 4) void attn_fwd(
    const unsigned short* __restrict__ Q,   // [B][H][T][HD], pre-scaled
    const unsigned short* __restrict__ Kg,
    const unsigned short* __restrict__ Vg,
    const int* __restrict__ pad,            // [B][T]
    unsigned short* __restrict__ Y)         // [B][T][C]
{
    __shared__ unsigned short smem[192 * DPAD];
    unsigned short* Kt = smem;               // [key][d]
    unsigned short* Vt = smem + 64 * DPAD;   // [d][key-swizzled]
    unsigned short* Pl = smem + 128 * DPAD;  // per-wave P slices

    int qpair = blockIdx.x;         // 0..15
    int bh = blockIdx.y;            // 0..63
    int b  = bh >> 4, h = bh & 15;
    const size_t base = (size_t)bh * Tt * HDd;
    int tid  = threadIdx.x;
    int wave = tid >> 6, lane = tid & 63;
    int lr = lane & 15, lg = lane >> 4;
    unsigned short* Pw = &Pl[wave * 16 * DPAD];
    const int* padRow = pad + b * Tt;

    int qbA = qpair, qbB = 31 - qpair;
    int q0A = qbA * 64 + wave * 16;
    int q0B = qbB * 64 + wave * 16;

    short8 qfA0 = *(const short8*)&Q[base + (size_t)(q0A + lr) * HDd + lg * 8];
    short8 qfA1 = *(const short8*)&Q[base + (size_t)(q0A + lr) * HDd + 32 + lg * 8];
    short8 qfB0 = *(const short8*)&Q[base + (size_t)(q0B + lr) * HDd + lg * 8];
    short8 qfB1 = *(const short8*)&Q[base + (size_t)(q0B + lr) * HDd + 32 + lg * 8];

    float mA[4], lA[4], mB[4], lB[4];
    float4_ oA[4], oB[4];
    #pragma unroll
    for (int r = 0; r < 4; r++) { mA[r] = -1e30f; lA[r] = 0.f; mB[r] = -1e30f; lB[r] = 0.f; }
    #pragma unroll
    for (int dt = 0; dt < 4; dt++) {
        oA[dt] = (float4_){0.f, 0.f, 0.f, 0.f};
        oB[dt] = (float4_){0.f, 0.f, 0.f, 0.f};
    }

    for (int kt = 0; kt <= qbB; kt++) {
        int k0 = kt * 64;
        // ---- stage K (as-is) and V (transposed, XOR key-block swizzle) ----
        {
            int r = tid >> 2, cbase = (tid & 3) * 8;
            #pragma unroll
            for (int half = 0; half < 2; half++) {
                int c = cbase + half * 32;
                *(short8*)&Kt[r * DPAD + c] =
                    *(const short8*)&Kg[base + (size_t)(k0 + r) * HDd + c];
                alignas(16) unsigned short tmp[8];
                *(short8*)tmp = *(const short8*)&Vg[base + (size_t)(k0 + r) * HDd + c];
                #pragma unroll
                for (int j = 0; j < 8; j++) {
                    int d = c + j;
                    Vt[d * DPAD + ((((r >> 3) ^ (d >> 3)) << 3) | (r & 7))] = tmp[j];
                }
            }
        }
        __syncthreads();

        // pad mask as additive constant, computed once, reused by both tiles
        float pmask[4];
        #pragma unroll
        for (int nt = 0; nt < 4; nt++)
            pmask[nt] = (padRow[k0 + nt * 16 + lr] != 0) ? 0.f : -1e30f;

        ATTN_TILE(q0B, qfB0, qfB1, mB, lB, oB);
        if (kt <= qbA)
            ATTN_TILE(q0A, qfA0, qfA1, mA, lA, oA);

        __syncthreads();
    }

    // ---- epilogue: Y[b][t][h*64+d] = O / l  (bf16) ----
    #pragma unroll
    for (int dt = 0; dt < 4; dt++)
        #pragma unroll
        for (int r = 0; r < 4; r++) {
            int qrowA = q0A + lg * 4 + r;
            int qrowB = q0B + lg * 4 + r;
            Y[((size_t)b * Tt + qrowA) * Cc + h * HDd + dt * 16 + lr] = f2bf(oA[dt][r] / lA[r]);
            Y[((size_t)b * Tt + qrowB) * Cc + h * HDd + dt * 16 + lr] = f2bf(oB[dt][r] / lB[r]);
        }
}

// ---------------------------------------------------------------------------
extern "C" void kernel_launch(void* const* d_in, const int* in_sizes, int n_in,
                              void* d_out, int out_size, void* d_ws, size_t ws_size,
                              hipStream_t stream)
{
    const float* x      = (const float*)d_in[0];
    const int*   pad    = (const int*)d_in[1];
    const float* w_attn = (const float*)d_in[2];
    const float* w_proj = (const float*)d_in[3];
    const float* b_proj = (const float*)d_in[4];
    float*       out    = (float*)d_out;

    // workspace carve-up (bf16 elems). Yb aliases Xb (x-bf16 dead after qkv).
    unsigned short* Wta = (unsigned short*)d_ws;            // 3072*1024
    unsigned short* Wtp = Wta + (size_t)3072 * 1024;        // 1024*1024
    unsigned short* Xb  = Wtp + (size_t)1024 * 1024;        // 8192*1024
    unsigned short* Yb  = Xb;                               // alias
    unsigned short* Qb  = Xb + (size_t)8192 * 1024;
    unsigned short* Kb  = Qb + (size_t)Bb * Hh * Tt * HDd;
    unsigned short* Vb  = Kb + (size_t)Bb * Hh * Tt * HDd;

    // 0) x f32 -> bf16
    convert_f32_bf16<<<dim3(4096), 256, 0, stream>>>(x, Xb);
    // 1) transpose+convert weights to bf16 [N][K]
    transpose_f32_bf16<<<dim3(3072 / 32, 1024 / 32), 256, 0, stream>>>(w_attn, Wta, 1024, 3072);
    transpose_f32_bf16<<<dim3(1024 / 32, 1024 / 32), 256, 0, stream>>>(w_proj, Wtp, 1024, 1024);
    // 2) qkv = x @ w_attn, scattered to head-major Q/K/V (bf16, Q pre-scaled)
    gemm_qkv<<<dim3(8192 / 128, 3072 / 128), 256, 0, stream>>>(Xb, Wta, Qb, Kb, Vb);
    // 3) flash attention, paired q-tiles (perfect balance)
    attn_fwd<<<dim3(16, Bb * Hh), 256, 0, stream>>>(Qb, Kb, Vb, pad, Yb);
    // 4) out = y @ w_proj + b_proj (f32 out)
    gemm_proj<<<dim3(8192 / 128, 1024 / 128), 256, 0, stream>>>(Yb, Wtp, b_proj, out);
}